// Round 10
// baseline (194.024 us; speedup 1.0000x reference)
//
#include <hip/hip_runtime.h>
#include <math.h>
#include <string.h>

#define EPSF 1e-6f
#define TCLIP (1.0f - 1e-5f)
#define NPTS 16384
#define DDIM 256
#define NBLK 128
#define NTHR 1024
#define PPB 128    // points per block
#define NWAVE 16
#define PPW 8      // points per wave (registers: 8 x float4 = 32 VGPRs)
#define PSTR 260   // row: 256 vec + sA@256 + wd@257 + tag@258 + pad
#define WSLICE (PPW * 65)   // 520-float private LDS slice per wave
#define FRECHET_ITERS_N 10

#define WS_PA 64
#define WS_PB (WS_PA + NBLK * PSTR)

// --- coherent-path (sc1) accessors ---
__device__ __forceinline__ void st_pair_sc1(float* addr, float a, float b) {
    float2 f2 = make_float2(a, b);
    double dv; memcpy(&dv, &f2, 8);
    __hip_atomic_store((double*)addr, dv, __ATOMIC_RELAXED, __HIP_MEMORY_SCOPE_AGENT);
}
__device__ __forceinline__ float2 ld_pair_sc1(const float* addr) {
    double dv = __hip_atomic_load((const double*)addr, __ATOMIC_RELAXED, __HIP_MEMORY_SCOPE_AGENT);
    float2 f2; memcpy(&f2, &dv, 8);
    return f2;
}
__device__ __forceinline__ void st_f_sc1(float* addr, float v) {
    __hip_atomic_store(addr, v, __ATOMIC_RELAXED, __HIP_MEMORY_SCOPE_AGENT);
}
__device__ __forceinline__ float ld_f_sc1(const float* addr) {
    return __hip_atomic_load(addr, __ATOMIC_RELAXED, __HIP_MEMORY_SCOPE_AGENT);
}
__device__ __forceinline__ void st_u_sc1(unsigned* addr, unsigned v) {
    __hip_atomic_store(addr, v, __ATOMIC_RELAXED, __HIP_MEMORY_SCOPE_AGENT);
}
__device__ __forceinline__ unsigned ld_u_sc1(const unsigned* addr) {
    return __hip_atomic_load(addr, __ATOMIC_RELAXED, __HIP_MEMORY_SCOPE_AGENT);
}

__device__ __forceinline__ float block_sum(float v) {
    __shared__ float s_bs[NWAVE];
    #pragma unroll
    for (int off = 32; off; off >>= 1) v += __shfl_xor(v, off);
    const int w = threadIdx.x >> 6, l = threadIdx.x & 63;
    __syncthreads();
    if (l == 0) s_bs[w] = v;
    __syncthreads();
    float s = 0.f;
    #pragma unroll
    for (int i = 0; i < NWAVE; ++i) s += s_bs[i];
    return s;
}

__global__ void init_tags(float* ws) {
    int t = threadIdx.x;
    if (t < NBLK) {
        st_u_sc1((unsigned*)(ws + WS_PA + t * PSTR + 258), 0u);
        st_u_sc1((unsigned*)(ws + WS_PB + t * PSTR + 258), 0u);
    }
}

__global__ __launch_bounds__(NTHR, 1) void rbn_fused(
    const float* __restrict__ x, const float* __restrict__ Kp,
    const float* __restrict__ mean_param, const float* __restrict__ var_param,
    float* __restrict__ out, float* __restrict__ ws)
{
    const float c = -Kp[0];
    const float sc = sqrtf(c);
    const float N1 = 1.f / NPTS;
    const int t = threadIdx.x, lane = t & 63, wv = t >> 6;
    const int b = blockIdx.x;
    const int p0 = b * PPB;
    const float4* xr = ((const float4*)x) + p0 * 64;

    float* PA = ws + WS_PA;
    float* PB = ws + WS_PB;

    __shared__ float mu_s[DDIM], om_s[DDIM];
    __shared__ float dpart[NWAVE * WSLICE];   // per-wave private slices
    __shared__ float pseg[NWAVE * DDIM];
    __shared__ float part1[NWAVE], part2[NWAVE], part3[NWAVE];

    unsigned barno = 0;

    // ---- register-resident x chunk ----
    float4 xreg[PPW];
    #pragma unroll
    for (int i = 0; i < PPW; ++i)
        xreg[i] = xr[(wv * PPW + i) * 64 + lane];

    // wave-local batched dot: returns <x_{wv*8+g}, v> at every lane (g=lane>>3).
    // No __syncthreads: the LDS slice is private to this wave.
    auto wave_dot = [&](float4 v4, bool self) -> float {
        float* slice = dpart + wv * WSLICE;
        #pragma unroll
        for (int i = 0; i < PPW; ++i) {
            float4 xv = xreg[i];
            float4 u4 = self ? xv : v4;
            slice[i * 65 + lane] = xv.x * u4.x + xv.y * u4.y + xv.z * u4.z + xv.w * u4.w;
        }
        const int g = lane >> 3, q = lane & 7;
        float s = 0.f;
        #pragma unroll
        for (int j = 0; j < 8; ++j) s += slice[g * 65 + q * 8 + j];
        #pragma unroll
        for (int off = 1; off <= 4; off <<= 1) s += __shfl_xor(s, off);
        return s;
    };
    // sum one representative per 8-lane group across the wave
    auto wave_sum_groups = [&](float v) -> float {
        #pragma unroll
        for (int off = 8; off <= 32; off <<= 1) v += __shfl_xor(v, off);
        return v;
    };

    auto poll_tags = [&](const float* buf) {
        if (t < NBLK) {
            const unsigned* tg = (const unsigned*)(buf + t * PSTR + 258);
            while (ld_u_sc1(tg) < barno)
                __builtin_amdgcn_s_sleep(1);
        }
        __syncthreads();
    };

    // ---- om = exp0(mean_param) ----
    {
        float u = (t < DDIM) ? mean_param[t] : 0.f;
        float un2 = block_sum(u * u);
        float un = sqrtf(fmaxf(un2, EPSF));
        if (t < DDIM) om_s[t] = tanhf(sc * un) * u / (sc * un);
    }
    float om2;
    { float v = (t < DDIM) ? om_s[t] * om_s[t] : 0.f; om2 = block_sum(v); }

    // ================= MEAN PHASE =================
    ++barno;
    {
        float4 a = make_float4(0.f, 0.f, 0.f, 0.f);
        #pragma unroll
        for (int i = 0; i < PPW; ++i) {
            a.x += xreg[i].x; a.y += xreg[i].y; a.z += xreg[i].z; a.w += xreg[i].w;
        }
        ((float4*)(pseg + wv * DDIM))[lane] = a;
    }
    __syncthreads();                          // M1
    {
        float s = 0.f;
        if (t < DDIM) {
            #pragma unroll
            for (int w = 0; w < NWAVE; ++w) s += pseg[w * DDIM + t];
        }
        float partner = __shfl_xor(s, 1);
        if (t < DDIM && !(t & 1)) st_pair_sc1(PA + b * PSTR + t, s, partner);
    }
    __syncthreads();                          // M2 drain
    if (t == 0) st_u_sc1((unsigned*)(PA + b * PSTR + 258), barno);

    // hidden, wave-local: y2 and e (kept in registers, value for point wv*8+(lane>>3))
    float y2r = wave_dot(make_float4(0.f, 0.f, 0.f, 0.f), true);
    float er;
    {
        float4 om4 = ((const float4*)om_s)[lane];
        er = wave_dot(om4, false);
    }
    poll_tags(PA);                            // M3

    float mu2;
    {
        const int dg = t & 127, sg = t >> 7;
        float ax = 0.f, ay = 0.f;
        #pragma unroll
        for (int j = 0; j < 16; ++j) {
            float2 v = ld_pair_sc1(PA + (sg * 16 + j) * PSTR + 2 * dg);
            ax += v.x; ay += v.y;
        }
        ((float2*)(pseg + sg * DDIM))[dg] = make_float2(ax, ay);
        __syncthreads();                      // M4
        float m = 0.f, mm = 0.f;
        if (t < DDIM) {
            float s = 0.f;
            #pragma unroll
            for (int w = 0; w < 8; ++w) s += pseg[w * DDIM + t];
            m = s * N1; mm = m * m;
        }
        #pragma unroll
        for (int off = 32; off; off >>= 1) mm += __shfl_xor(mm, off);
        if (lane == 0) part1[wv] = mm;
        __syncthreads();                      // M5
        float mn2 = 0.f;
        #pragma unroll
        for (int i = 0; i < NWAVE; ++i) mn2 += part1[i];
        float mn = sqrtf(fmaxf(mn2, EPSF));
        float maxn = (1.f - 1e-3f) / sc;
        float f = fminf(1.f, maxn / mn);
        if (t < DDIM) mu_s[t] = m * f;
        mu2 = f * f * mn2;
        __syncthreads();                      // M6 mu_s visible
    }

    // ================= KARCHER ITERATIONS (6 syncs each) =================
    for (int it = 0; it < FRECHET_ITERS_N; ++it) {
        float* buf = (it & 1) ? PA : PB;
        ++barno;
        float4 mu4 = ((const float4*)mu_s)[lane];
        float d = wave_dot(mu4, false);
        // scalar chain, redundant within each 8-lane group (all waves active)
        float w, sA;
        {
            float y2 = y2r;
            float P = 1.f - 2.f * c * d;
            float den = fmaxf(P + c * c * mu2 * y2, EPSF);
            float A = -(P + c * y2) / den;
            float B = (1.f - c * mu2) / den;
            float mn2 = fmaxf(A * A * mu2 + 2.f * A * B * d + B * B * y2, EPSF);
            float mn = sqrtf(mn2);
            float tt = atanhf(fminf(sc * mn, TCLIP));
            float s = (fmaxf(1.f - c * mu2, EPSF) / sc) * tt / mn;
            w = s * B;
            sA = s * A;
        }
        // weighted sum via shuffle broadcast of w
        {
            float4 a = make_float4(0.f, 0.f, 0.f, 0.f);
            #pragma unroll
            for (int i = 0; i < PPW; ++i) {
                float wi = __shfl(w, i * 8);
                a.x += wi * xreg[i].x; a.y += wi * xreg[i].y;
                a.z += wi * xreg[i].z; a.w += wi * xreg[i].w;
            }
            ((float4*)(pseg + wv * DDIM))[lane] = a;
        }
        float sAw = wave_sum_groups(sA);
        float wdw = wave_sum_groups(w * d);
        if (lane == 0) { part1[wv] = sAw; part2[wv] = wdw; }
        __syncthreads();                      // S1
        // column sums + publish
        {
            float s = 0.f;
            if (t < DDIM) {
                #pragma unroll
                for (int w2 = 0; w2 < NWAVE; ++w2) s += pseg[w2 * DDIM + t];
            }
            float partner = __shfl_xor(s, 1);
            if (t < DDIM && !(t & 1)) st_pair_sc1(buf + b * PSTR + t, s, partner);
            if (t == 0) {
                float sa = 0.f, wd = 0.f;
                #pragma unroll
                for (int i = 0; i < NWAVE; ++i) { sa += part1[i]; wd += part2[i]; }
                st_pair_sc1(buf + b * PSTR + 256, sa, wd);
            }
        }
        __syncthreads();                      // S2 drain
        if (t == 0) st_u_sc1((unsigned*)(buf + b * PSTR + 258), barno);
        poll_tags(buf);                       // S3
        // gather
        const int dg = t & 127, sg = t >> 7;
        float ax = 0.f, ay = 0.f;
        #pragma unroll
        for (int j = 0; j < 16; ++j) {
            float2 v = ld_pair_sc1(buf + (sg * 16 + j) * PSTR + 2 * dg);
            ax += v.x; ay += v.y;
        }
        float2 sp = make_float2(0.f, 0.f);
        if (t < NBLK) sp = ld_pair_sc1(buf + t * PSTR + 256);
        ((float2*)(pseg + sg * DDIM))[dg] = make_float2(ax, ay);
        __syncthreads();                      // S4
        float g = 0.f, vvv = 0.f;
        if (t < DDIM) {
            #pragma unroll
            for (int w2 = 0; w2 < 8; ++w2) g += pseg[w2 * DDIM + t];
            vvv = g * g;
        }
        float sAt = sp.x, wdt = sp.y;
        #pragma unroll
        for (int off = 32; off; off >>= 1) {
            vvv += __shfl_xor(vvv, off); sAt += __shfl_xor(sAt, off); wdt += __shfl_xor(wdt, off);
        }
        if (lane == 0) { part1[wv] = vvv; part2[wv] = sAt; part3[wv] = wdt; }
        __syncthreads();                      // S5
        float vv = 0.f, sa = 0.f, wd = 0.f;
        #pragma unroll
        for (int i = 0; i < NWAVE; ++i) { vv += part1[i]; sa += part2[i]; wd += part3[i]; }
        float gn2 = N1 * N1 * (vv + 2.f * sa * wd + sa * sa * mu2);
        float mg  = N1 * (wd + sa * mu2);
        float un = sqrtf(fmaxf(gn2, EPSF));
        float lam = 2.f / fmaxf(1.f - c * mu2, EPSF);
        float k = tanhf(sc * lam * un * 0.5f) / (sc * un);
        float ms = k * mg;
        float s2 = k * k * gn2;
        float aa = 1.f + 2.f * c * ms + c * s2;
        float bb2 = 1.f - c * mu2;
        float den = fmaxf(1.f + 2.f * c * ms + c * c * mu2 * s2, EPSF);
        float cm = (aa + bb2 * k * N1 * sa) / den;
        float cv = (bb2 * k * N1) / den;
        if (t < DDIM) mu_s[t] = cm * mu_s[t] + cv * g;
        mu2 = cm * cm * mu2 + 2.f * cm * cv * wd + cv * cv * vv;
        __syncthreads();                      // S6 mu_s visible
    }

    // ================= VARIANCE + OUTPUT =================
    float* vbuf = ((FRECHET_ITERS_N - 1) & 1) ? PB : PA;
    ++barno;
    float4 mu4f = ((const float4*)mu_s)[lane];
    float4 om4f = ((const float4*)om_s)[lane];
    float d = wave_dot(mu4f, false);          // kept in register
    float vval;
    {
        float y2 = y2r;
        float P = 1.f - 2.f * c * d;
        float den = fmaxf(P + c * c * mu2 * y2, EPSF);
        float A = -(P + c * y2) / den;
        float B = (1.f - c * mu2) / den;
        float mn2 = fmaxf(A * A * mu2 + 2.f * A * B * d + B * B * y2, EPSF);
        float mn = sqrtf(mn2);
        float tt = atanhf(fminf(sc * mn, TCLIP));
        float dd = (2.f / sc) * tt;
        vval = dd * dd;
    }
    {
        float vw = wave_sum_groups(vval);     // this wave's 8 points
        float ov = (t < DDIM) ? om_s[t] * mu_s[t] : 0.f;
        #pragma unroll
        for (int off = 32; off; off >>= 1) ov += __shfl_xor(ov, off);
        if (lane == 0) { part1[wv] = vw; part2[wv] = ov; }
    }
    __syncthreads();                          // V1
    if (t == 0) {
        float tot = 0.f;
        #pragma unroll
        for (int i = 0; i < NWAVE; ++i) tot += part1[i];
        st_f_sc1(vbuf + b * PSTR + 256, tot);
    }
    __syncthreads();                          // V2 drain
    if (t == 0) st_u_sc1((unsigned*)(vbuf + b * PSTR + 258), barno);

    float omu = 0.f;
    #pragma unroll
    for (int i = 0; i < NWAVE; ++i) omu += part2[i];

    const float Amu = fmaxf(1.f - c * mu2, EPSF);
    const float Aom = fmaxf(1.f - c * om2, EPSF);
    const float ratio = Aom / Amu;
    const float aq = 1.f - 2.f * c * omu + c * mu2;
    const float bq = 1.f - c * om2;
    const float dqv = fmaxf(1.f - 2.f * c * omu + c * c * om2 * mu2, EPSF);
    const float qo = aq / dqv, qm = -bq / dqv;
    const float q2 = qo * qo * om2 + 2.f * qo * qm * omu + qm * qm * mu2;
    const float lam_om = 2.f / Aom;

    // hidden, wave-local: gamma-independent output stages (per 8-lane group)
    float g2o, g2m, g2x;
    {
        float y2 = y2r, e = er;
        auto dotOm3 = [&](float po, float pm, float px) { return po * om2 + pm * omu + px * e; };
        auto dotMu3 = [&](float po, float pm, float px) { return po * omu + pm * mu2 + px * d; };
        auto sqn3 = [&](float po, float pm, float px) {
            return po * po * om2 + pm * pm * mu2 + px * px * y2
                 + 2.f * (po * pm * omu + po * px * e + pm * px * d);
        };
        float P = 1.f - 2.f * c * d;
        float den0 = fmaxf(P + c * c * mu2 * y2, EPSF);
        float A = -(P + c * y2) / den0;
        float B = (1.f - c * mu2) / den0;
        float mn2 = fmaxf(A * A * mu2 + 2.f * A * B * d + B * B * y2, EPSF);
        float mn = sqrtf(mn2);
        float tt = atanhf(fminf(sc * mn, TCLIP));
        float s = (fmaxf(1.f - c * mu2, EPSF) / sc) * tt / mn;
        float Um = s * A, Ux = s * B;

        float xy1 = -dotMu3(0.f, Um, Ux);
        float Y21 = sqn3(0.f, Um, Ux);
        float a1 = 1.f + 2.f * c * xy1 + c * Y21;
        float b1 = 1.f - c * mu2;
        float dn1 = fmaxf(1.f + 2.f * c * xy1 + c * c * mu2 * Y21, EPSF);
        float h1m = (-a1 + b1 * Um) / dn1;
        float h1x = (b1 * Ux) / dn1;

        float xy2 = dotOm3(0.f, h1m, h1x);
        float Y22 = sqn3(0.f, h1m, h1x);
        float a2 = 1.f + 2.f * c * xy2 + c * Y22;
        float b2 = 1.f - c * om2;
        float dn2 = fmaxf(1.f + 2.f * c * xy2 + c * c * om2 * Y22, EPSF);
        float h2o = a2 / dn2;
        float h2m = (b2 * h1m) / dn2;
        float h2x = (b2 * h1x) / dn2;

        float xy3 = -(qo * dotOm3(h2o, h2m, h2x) + qm * dotMu3(h2o, h2m, h2x));
        float Y23 = sqn3(h2o, h2m, h2x);
        float a3 = 1.f + 2.f * c * xy3 + c * Y23;
        float b3 = 1.f - c * q2;
        float dn3 = fmaxf(1.f + 2.f * c * xy3 + c * c * q2 * Y23, EPSF);
        g2o = (-a3 * qo + b3 * h2o) / dn3;
        g2m = (-a3 * qm + b3 * h2m) / dn3;
        g2x = (b3 * h2x) / dn3;
    }
    poll_tags(vbuf);                          // V3

    // var gather (scalar)
    {
        float va = (t < NBLK) ? ld_f_sc1(vbuf + t * PSTR + 256) : 0.f;
        #pragma unroll
        for (int off = 32; off; off >>= 1) va += __shfl_xor(va, off);
        if (lane == 0) part1[wv] = va;
    }
    __syncthreads();                          // V4
    float vsum = 0.f;
    #pragma unroll
    for (int i = 0; i < NWAVE; ++i) vsum += part1[i];
    float var = vsum * N1;
    float gamma = sqrtf(var_param[0] / (var + 1e-6f));

    // gamma-dependent tail, wave-local
    float fo, fm, fx;
    {
        float y2 = y2r, e = er;
        float k1 = ratio * gamma;
        float Lo = k1 * g2o, Lm = k1 * g2m, Lx = k1 * g2x;
        float un2 = Lo * Lo * om2 + Lm * Lm * mu2 + Lx * Lx * y2
                  + 2.f * (Lo * Lm * omu + Lo * Lx * e + Lm * Lx * d);
        float un = sqrtf(fmaxf(un2, EPSF));
        float coef = tanhf(sc * lam_om * un * 0.5f) / (sc * un);
        float So = coef * Lo, Sm = coef * Lm, Sx = coef * Lx;
        float xy4 = So * om2 + Sm * omu + Sx * e;
        float Y24 = coef * coef * un2;
        float a4 = 1.f + 2.f * c * xy4 + c * Y24;
        float b4 = 1.f - c * om2;
        float dn4 = fmaxf(1.f + 2.f * c * xy4 + c * c * om2 * Y24, EPSF);
        fo = (a4 + b4 * So) / dn4;
        fm = (b4 * Sm) / dn4;
        fx = (b4 * Sx) / dn4;
    }

    // output store: broadcast fo/fm/fx from each group's lane, float4 coalesced
    #pragma unroll
    for (int i = 0; i < PPW; ++i) {
        float foi = __shfl(fo, i * 8);
        float fmi = __shfl(fm, i * 8);
        float fxi = __shfl(fx, i * 8);
        float4 x4 = xreg[i];
        float4 o4;
        o4.x = foi * om4f.x + fmi * mu4f.x + fxi * x4.x;
        o4.y = foi * om4f.y + fmi * mu4f.y + fxi * x4.y;
        o4.z = foi * om4f.z + fmi * mu4f.z + fxi * x4.z;
        o4.w = foi * om4f.w + fmi * mu4f.w + fxi * x4.w;
        ((float4*)out)[(p0 + wv * PPW + i) * 64 + lane] = o4;
    }
}

extern "C" void kernel_launch(void* const* d_in, const int* in_sizes, int n_in,
                              void* d_out, int out_size, void* d_ws, size_t ws_size,
                              hipStream_t stream) {
    const float* x = (const float*)d_in[0];
    const float* K = (const float*)d_in[1];
    const float* mean_param = (const float*)d_in[2];
    const float* var_param = (const float*)d_in[3];
    float* out = (float*)d_out;
    float* ws = (float*)d_ws;

    init_tags<<<1, 256, 0, stream>>>(ws);
    void* args[] = {(void*)&x, (void*)&K, (void*)&mean_param, (void*)&var_param,
                    (void*)&out, (void*)&ws};
    hipLaunchCooperativeKernel((const void*)rbn_fused, dim3(NBLK), dim3(NTHR),
                               args, 0, stream);
}